// Round 1
// baseline (883.736 us; speedup 1.0000x reference)
//
#include <hip/hip_runtime.h>
#include <cstdint>
#include <cstdio>

typedef unsigned short u16;
typedef short bf16x8 __attribute__((ext_vector_type(8)));
typedef float f32x4 __attribute__((ext_vector_type(4)));
typedef unsigned short u16x8 __attribute__((ext_vector_type(8)));

#define SEQL 2048
#define NHEADS 32
#define HDIM 128
#define HIDDEN 4096

__device__ __forceinline__ u16 f2bf(float x){
  union { float f; unsigned u; } v; v.f = x;
  unsigned r = v.u + 0x7fffu + ((v.u >> 16) & 1u);
  return (u16)(r >> 16);
}
__device__ __forceinline__ float bf2f(u16 x){
  union { unsigned u; float f; } v; v.u = ((unsigned)x) << 16;
  return v.f;
}

__device__ __forceinline__ void gload_lds16(const u16* g, u16* l){
  __builtin_amdgcn_global_load_lds((const __attribute__((address_space(1))) void*)g,
                                   (__attribute__((address_space(3))) void*)l, 16, 0, 0);
}

// ---------------- cast hidden_states f32 -> bf16 ----------------
__global__ void cast_hs_kernel(const float* __restrict__ in, u16* __restrict__ out, int n8){
  int i = blockIdx.x * blockDim.x + threadIdx.x;
  if (i >= n8) return;
  const float4* p = (const float4*)in + (size_t)i*2;
  float4 a = p[0], b = p[1];
  u16x8 o;
  o[0]=f2bf(a.x); o[1]=f2bf(a.y); o[2]=f2bf(a.z); o[3]=f2bf(a.w);
  o[4]=f2bf(b.x); o[5]=f2bf(b.y); o[6]=f2bf(b.z); o[7]=f2bf(b.w);
  *((u16x8*)out + i) = o;
}

// ---------------- transpose + cast weight chunk: W[K][Ntot] f32 -> Wt[n][k] bf16 ----------------
__global__ void wtrans_kernel(const float* __restrict__ W, u16* __restrict__ Wt,
                              int Ntot, int n0, int K){
  __shared__ float t[32][33];
  int tx = threadIdx.x, ty = threadIdx.y;
  int nn = blockIdx.x*32, k0 = blockIdx.y*32;
  #pragma unroll
  for (int i=0;i<4;i++)
    t[ty*4+i][tx] = W[(size_t)(k0+ty*4+i)*Ntot + n0 + nn + tx];
  __syncthreads();
  #pragma unroll
  for (int i=0;i<4;i++)
    Wt[(size_t)(nn+ty*4+i)*K + k0 + tx] = f2bf(t[tx][ty*4+i]);
}

// ---------------- m97-style GEMM: C = A[M][K] * Bt[N][K]^T + bias ----------------
template<int OUT_BF16>
__global__ __launch_bounds__(256) void gemm_bt_kernel(const u16* __restrict__ A, const u16* __restrict__ Bt,
                               const float* __restrict__ bias, void* __restrict__ Cv,
                               int M, int N, int K, int ldC)
{
  __shared__ u16 lA[128*32];
  __shared__ u16 lB[128*32];
  int tid = threadIdx.x;
  int lane = tid & 63;
  int wave = tid >> 6;
  int lr = lane & 15, lg = lane >> 4;
  int m0 = blockIdx.y*128, n0 = blockIdx.x*128;
  int wr = (wave >> 1)*64, wc = (wave & 1)*64;
  f32x4 acc[4][4] = {};
  for (int k0 = 0; k0 < K; k0 += 32){
    __syncthreads();
    #pragma unroll
    for (int i=0;i<2;i++){
      int c = i*256 + tid;
      gload_lds16(A + (size_t)(m0 + (c>>2))*K + k0 + (c&3)*8, &lA[c*8]);
    }
    #pragma unroll
    for (int i=0;i<2;i++){
      int c = i*256 + tid;
      gload_lds16(Bt + (size_t)(n0 + (c>>2))*K + k0 + (c&3)*8, &lB[c*8]);
    }
    __syncthreads();
    bf16x8 af[4], bfr[4];
    #pragma unroll
    for (int m=0;m<4;m++) af[m] = *(const bf16x8*)&lA[(wr + m*16 + lr)*32 + lg*8];
    #pragma unroll
    for (int n=0;n<4;n++) bfr[n] = *(const bf16x8*)&lB[(wc + n*16 + lr)*32 + lg*8];
    #pragma unroll
    for (int m=0;m<4;m++){
      #pragma unroll
      for (int n=0;n<4;n++){
        acc[m][n] = __builtin_amdgcn_mfma_f32_16x16x32_bf16(af[m], bfr[n], acc[m][n], 0, 0, 0);
      }
    }
  }
  #pragma unroll
  for (int m=0;m<4;m++){
    #pragma unroll
    for (int n=0;n<4;n++){
      #pragma unroll
      for (int j=0;j<4;j++){
        int gr = m0 + wr + m*16 + lg*4 + j;
        int gc = n0 + wc + n*16 + lr;
        float v = acc[m][n][j] + bias[gc];
        if (OUT_BF16) ((u16*)Cv)[(size_t)gr*ldC + gc] = f2bf(v);
        else          ((float*)Cv)[(size_t)gr*ldC + gc] = v;
      }
    }
  }
}

// ---------------- RoPE + relayout: qkv[s][h*384 + {0,128,256} + d] -> Q/K/V [h][s][d] ----------------
__global__ __launch_bounds__(64) void rope_kernel(const u16* __restrict__ qkv, const int* __restrict__ pos,
                            u16* __restrict__ Q, u16* __restrict__ Kc, u16* __restrict__ V)
{
  int s = blockIdx.x, h = blockIdx.y;
  int i = threadIdx.x;
  int half = i >> 5, ii = i & 31;
  int d0 = half*64 + ii*2;
  const u16* base = qkv + (size_t)s*12288 + h*384;
  unsigned qp = *(const unsigned*)&base[d0];
  unsigned kp = *(const unsigned*)&base[128 + d0];
  unsigned vp = *(const unsigned*)&base[256 + d0];
  float qe = bf2f((u16)qp), qo = bf2f((u16)(qp >> 16));
  float ke = bf2f((u16)kp), ko = bf2f((u16)(kp >> 16));
  float pv = (float)(pos[half*SEQL + s] + 1);
  float fr = exp2f(-(float)ii * 0.4152410118609203f);  // 10000^(-ii/32)
  float ang = pv * fr;
  float sn, cs; sincosf(ang, &sn, &cs);
  const float sc = 0.08838834764831845f;  // 1/sqrt(128), folded into Q
  float q0 = (qe*cs - qo*sn)*sc, q1 = (qe*sn + qo*cs)*sc;
  float k0 = ke*cs - ko*sn,      k1 = ke*sn + ko*cs;
  size_t ob = ((size_t)h*SEQL + s)*HDIM + d0;
  *(unsigned*)&Q[ob]  = (unsigned)f2bf(q0) | ((unsigned)f2bf(q1) << 16);
  *(unsigned*)&Kc[ob] = (unsigned)f2bf(k0) | ((unsigned)f2bf(k1) << 16);
  *(unsigned*)&V[ob]  = vp;
}

// ---------------- V -> V^T per head: [h][s][d] -> [h][d][s] ----------------
__global__ void vtrans_kernel(const u16* __restrict__ V, u16* __restrict__ Vt){
  __shared__ u16 t[32][33];
  int h = blockIdx.z;
  int d0 = blockIdx.x*32, s0 = blockIdx.y*32;
  int tx = threadIdx.x, ty = threadIdx.y;
  const u16* Vh = V + (size_t)h*SEQL*HDIM;
  u16* Vth = Vt + (size_t)h*HDIM*SEQL;
  #pragma unroll
  for (int i=0;i<4;i++)
    t[ty*4+i][tx] = Vh[(size_t)(s0+ty*4+i)*HDIM + d0 + tx];
  __syncthreads();
  #pragma unroll
  for (int i=0;i<4;i++)
    Vth[(size_t)(d0+ty*4+i)*SEQL + s0 + tx] = t[tx][ty*4+i];
}

// ---------------- causal flash attention: 1 wave = 16 q-rows ----------------
__global__ __launch_bounds__(64) void attn_kernel(const u16* __restrict__ Q, const u16* __restrict__ Kc,
                            const u16* __restrict__ Vt, u16* __restrict__ ctx)
{
  __shared__ u16 P[16*32];
  int qg = blockIdx.x, h = blockIdx.y;
  int q0 = qg*16;
  int lane = threadIdx.x;
  int lr = lane & 15, lg = lane >> 4;
  const u16* Qh = Q  + (size_t)h*SEQL*HDIM;
  const u16* Kh = Kc + (size_t)h*SEQL*HDIM;
  const u16* Vh = Vt + (size_t)h*HDIM*SEQL;
  bf16x8 qf[4];
  #pragma unroll
  for (int k32=0;k32<4;k32++)
    qf[k32] = *(const bf16x8*)&Qh[(size_t)(q0+lr)*HDIM + k32*32 + lg*8];
  f32x4 o[8] = {};
  float mrun[4], lrun[4];
  #pragma unroll
  for (int j=0;j<4;j++){ mrun[j] = -1e30f; lrun[j] = 0.f; }
  for (int t0 = 0; t0 <= q0 + 15; t0 += 32){
    f32x4 s0v = {}, s1v = {};
    #pragma unroll
    for (int k32=0;k32<4;k32++){
      bf16x8 kf = *(const bf16x8*)&Kh[(size_t)(t0 + lr)*HDIM + k32*32 + lg*8];
      s0v = __builtin_amdgcn_mfma_f32_16x16x32_bf16(qf[k32], kf, s0v, 0, 0, 0);
    }
    #pragma unroll
    for (int k32=0;k32<4;k32++){
      bf16x8 kf = *(const bf16x8*)&Kh[(size_t)(t0 + 16 + lr)*HDIM + k32*32 + lg*8];
      s1v = __builtin_amdgcn_mfma_f32_16x16x32_bf16(qf[k32], kf, s1v, 0, 0, 0);
    }
    #pragma unroll
    for (int j=0;j<4;j++){
      int row = q0 + lg*4 + j;
      float a = ((t0 + lr)      > row) ? -1e30f : s0v[j];
      float b = ((t0 + 16 + lr) > row) ? -1e30f : s1v[j];
      float mx = fmaxf(a, b);
      mx = fmaxf(mx, __shfl_xor(mx, 1));
      mx = fmaxf(mx, __shfl_xor(mx, 2));
      mx = fmaxf(mx, __shfl_xor(mx, 4));
      mx = fmaxf(mx, __shfl_xor(mx, 8));
      float mnew = fmaxf(mrun[j], mx);
      float scl = expf(mrun[j] - mnew);
      float p0 = expf(a - mnew);
      float p1 = expf(b - mnew);
      float sm = p0 + p1;
      sm += __shfl_xor(sm, 1);
      sm += __shfl_xor(sm, 2);
      sm += __shfl_xor(sm, 4);
      sm += __shfl_xor(sm, 8);
      lrun[j] = lrun[j]*scl + sm;
      mrun[j] = mnew;
      #pragma unroll
      for (int n=0;n<8;n++) o[n][j] *= scl;
      P[(lg*4+j)*32 + lr]      = f2bf(p0);
      P[(lg*4+j)*32 + 16 + lr] = f2bf(p1);
    }
    bf16x8 pa = *(const bf16x8*)&P[lr*32 + lg*8];
    #pragma unroll
    for (int n=0;n<8;n++){
      bf16x8 vf = *(const bf16x8*)&Vh[(size_t)(n*16 + lr)*SEQL + t0 + lg*8];
      o[n] = __builtin_amdgcn_mfma_f32_16x16x32_bf16(pa, vf, o[n], 0, 0, 0);
    }
  }
  #pragma unroll
  for (int j=0;j<4;j++){
    float inv = 1.f / lrun[j];
    int srow = q0 + lg*4 + j;
    #pragma unroll
    for (int n=0;n<8;n++)
      ctx[(size_t)srow*HIDDEN + h*HDIM + n*16 + lr] = f2bf(o[n][j]*inv);
  }
}

extern "C" void kernel_launch(void* const* d_in, const int* in_sizes, int n_in,
                              void* d_out, int out_size, void* d_ws, size_t ws_size,
                              hipStream_t stream)
{
  const float* hs   = (const float*)d_in[0];
  const int*   pos  = (const int*)d_in[1];
  const float* Wqkv = (const float*)d_in[2];
  const float* bqkv = (const float*)d_in[3];
  const float* Wd   = (const float*)d_in[4];
  const float* bd   = (const float*)d_in[5];

  const size_t o_Wt  = 0;           // 33,554,432 B (4096x4096 bf16, reused 4x)
  const size_t o_hs  = 33554432;    // 16,777,216 B
  const size_t o_qkv = 50331648;    // 50,331,648 B (2048x12288 bf16); ctx aliases this
  const size_t o_Q   = 100663296;   // 16,777,216 B each
  const size_t o_K   = 117440512;
  const size_t o_V   = 134217728;
  const size_t o_Vt  = 150994944;
  const size_t need  = 167772160;
  if (ws_size < need){
    fprintf(stderr, "kernel_launch: ws too small: %zu < %zu\n", ws_size, need);
    return;
  }
  char* w = (char*)d_ws;
  u16* Wt  = (u16*)(w + o_Wt);
  u16* hsb = (u16*)(w + o_hs);
  u16* qkv = (u16*)(w + o_qkv);
  u16* ctx = (u16*)(w + o_qkv);   // alias: qkv dead after rope
  u16* Qs  = (u16*)(w + o_Q);
  u16* Ks  = (u16*)(w + o_K);
  u16* Vs  = (u16*)(w + o_V);
  u16* Vts = (u16*)(w + o_Vt);

  cast_hs_kernel<<<dim3(4096), dim3(256), 0, stream>>>(hs, hsb, SEQL*HIDDEN/8);

  for (int c = 0; c < 3; ++c){
    wtrans_kernel<<<dim3(128,128), dim3(32,8), 0, stream>>>(Wqkv, Wt, 12288, c*4096, 4096);
    gemm_bt_kernel<1><<<dim3(32,16), dim3(256), 0, stream>>>(
        hsb, Wt, bqkv + c*4096, (void*)(qkv + (size_t)c*4096), SEQL, 4096, HIDDEN, 12288);
  }

  rope_kernel<<<dim3(SEQL, NHEADS), dim3(64), 0, stream>>>(qkv, pos, Qs, Ks, Vs);
  vtrans_kernel<<<dim3(4, 64, NHEADS), dim3(32,8), 0, stream>>>(Vs, Vts);
  attn_kernel<<<dim3(SEQL/16, NHEADS), dim3(64), 0, stream>>>(Qs, Ks, Vts, ctx);

  wtrans_kernel<<<dim3(128,128), dim3(32,8), 0, stream>>>(Wd, Wt, 4096, 0, 4096);
  gemm_bt_kernel<0><<<dim3(32,16), dim3(256), 0, stream>>>(
      ctx, Wt, bd, d_out, SEQL, HIDDEN, HIDDEN, HIDDEN);
}

// Round 2
// 777.990 us; speedup vs baseline: 1.1359x; 1.1359x over previous
//
#include <hip/hip_runtime.h>
#include <cstdint>
#include <cstdio>

typedef unsigned short u16;
typedef short bf16x8 __attribute__((ext_vector_type(8)));
typedef float f32x4 __attribute__((ext_vector_type(4)));
typedef unsigned short u16x8 __attribute__((ext_vector_type(8)));

#define SEQL 2048
#define NHEADS 32
#define HDIM 128
#define HIDDEN 4096

__device__ __forceinline__ u16 f2bf(float x){
  union { float f; unsigned u; } v; v.f = x;
  unsigned r = v.u + 0x7fffu + ((v.u >> 16) & 1u);
  return (u16)(r >> 16);
}
__device__ __forceinline__ float bf2f(u16 x){
  union { unsigned u; float f; } v; v.u = ((unsigned)x) << 16;
  return v.f;
}

__device__ __forceinline__ void gload_lds16(const u16* g, u16* l){
  __builtin_amdgcn_global_load_lds((const __attribute__((address_space(1))) void*)g,
                                   (__attribute__((address_space(3))) void*)l, 16, 0, 0);
}

// ---------------- cast hidden_states f32 -> bf16 ----------------
__global__ void cast_hs_kernel(const float* __restrict__ in, u16* __restrict__ out, int n8){
  int i = blockIdx.x * blockDim.x + threadIdx.x;
  if (i >= n8) return;
  const float4* p = (const float4*)in + (size_t)i*2;
  float4 a = p[0], b = p[1];
  u16x8 o;
  o[0]=f2bf(a.x); o[1]=f2bf(a.y); o[2]=f2bf(a.z); o[3]=f2bf(a.w);
  o[4]=f2bf(b.x); o[5]=f2bf(b.y); o[6]=f2bf(b.z); o[7]=f2bf(b.w);
  *((u16x8*)out + i) = o;
}

// ---------------- transpose + cast weight chunk: W[K][Ntot] f32 -> Wt[n][k] bf16 ----------------
__global__ void wtrans_kernel(const float* __restrict__ W, u16* __restrict__ Wt,
                              int Ntot, int n0, int K){
  __shared__ float t[32][33];
  int tx = threadIdx.x, ty = threadIdx.y;
  int nn = blockIdx.x*32, k0 = blockIdx.y*32;
  #pragma unroll
  for (int i=0;i<4;i++)
    t[ty*4+i][tx] = W[(size_t)(k0+ty*4+i)*Ntot + n0 + nn + tx];
  __syncthreads();
  #pragma unroll
  for (int i=0;i<4;i++)
    Wt[(size_t)(nn+ty*4+i)*K + k0 + tx] = f2bf(t[tx][ty*4+i]);
}

// ---------------- m97-style GEMM: C = A[M][K] * Bt[N][K]^T + bias ----------------
template<int OUT_BF16>
__global__ __launch_bounds__(256) void gemm_bt_kernel(const u16* __restrict__ A, const u16* __restrict__ Bt,
                               const float* __restrict__ bias, void* __restrict__ Cv,
                               int M, int N, int K, int ldC)
{
  __shared__ u16 lA[128*32];
  __shared__ u16 lB[128*32];
  int tid = threadIdx.x;
  int lane = tid & 63;
  int wave = tid >> 6;
  int lr = lane & 15, lg = lane >> 4;
  int m0 = blockIdx.y*128, n0 = blockIdx.x*128;
  int wr = (wave >> 1)*64, wc = (wave & 1)*64;
  f32x4 acc[4][4] = {};
  for (int k0 = 0; k0 < K; k0 += 32){
    __syncthreads();
    #pragma unroll
    for (int i=0;i<2;i++){
      int c = i*256 + tid;
      gload_lds16(A + (size_t)(m0 + (c>>2))*K + k0 + (c&3)*8, &lA[c*8]);
    }
    #pragma unroll
    for (int i=0;i<2;i++){
      int c = i*256 + tid;
      gload_lds16(Bt + (size_t)(n0 + (c>>2))*K + k0 + (c&3)*8, &lB[c*8]);
    }
    __syncthreads();
    bf16x8 af[4], bfr[4];
    #pragma unroll
    for (int m=0;m<4;m++) af[m] = *(const bf16x8*)&lA[(wr + m*16 + lr)*32 + lg*8];
    #pragma unroll
    for (int n=0;n<4;n++) bfr[n] = *(const bf16x8*)&lB[(wc + n*16 + lr)*32 + lg*8];
    #pragma unroll
    for (int m=0;m<4;m++){
      #pragma unroll
      for (int n=0;n<4;n++){
        acc[m][n] = __builtin_amdgcn_mfma_f32_16x16x32_bf16(af[m], bfr[n], acc[m][n], 0, 0, 0);
      }
    }
  }
  #pragma unroll
  for (int m=0;m<4;m++){
    #pragma unroll
    for (int n=0;n<4;n++){
      #pragma unroll
      for (int j=0;j<4;j++){
        int gr = m0 + wr + m*16 + lg*4 + j;
        int gc = n0 + wc + n*16 + lr;
        float v = acc[m][n][j] + bias[gc];
        if (OUT_BF16) ((u16*)Cv)[(size_t)gr*ldC + gc] = f2bf(v);
        else          ((float*)Cv)[(size_t)gr*ldC + gc] = v;
      }
    }
  }
}

// ---------------- RoPE + relayout: qkv[s][h*384 + {0,128,256} + d] -> Q/K/V [h][s][d] ----------------
__global__ __launch_bounds__(64) void rope_kernel(const u16* __restrict__ qkv, const int* __restrict__ pos,
                            u16* __restrict__ Q, u16* __restrict__ Kc, u16* __restrict__ V)
{
  int s = blockIdx.x, h = blockIdx.y;
  int i = threadIdx.x;
  int half = i >> 5, ii = i & 31;
  int d0 = half*64 + ii*2;
  const u16* base = qkv + (size_t)s*12288 + h*384;
  unsigned qp = *(const unsigned*)&base[d0];
  unsigned kp = *(const unsigned*)&base[128 + d0];
  unsigned vp = *(const unsigned*)&base[256 + d0];
  float qe = bf2f((u16)qp), qo = bf2f((u16)(qp >> 16));
  float ke = bf2f((u16)kp), ko = bf2f((u16)(kp >> 16));
  float pv = (float)(pos[half*SEQL + s] + 1);
  float fr = exp2f(-(float)ii * 0.4152410118609203f);  // 10000^(-ii/32)
  float ang = pv * fr;
  float sn, cs; sincosf(ang, &sn, &cs);
  const float sc = 0.08838834764831845f;  // 1/sqrt(128), folded into Q
  float q0 = (qe*cs - qo*sn)*sc, q1 = (qe*sn + qo*cs)*sc;
  float k0 = ke*cs - ko*sn,      k1 = ke*sn + ko*cs;
  size_t ob = ((size_t)h*SEQL + s)*HDIM + d0;
  *(unsigned*)&Q[ob]  = (unsigned)f2bf(q0) | ((unsigned)f2bf(q1) << 16);
  *(unsigned*)&Kc[ob] = (unsigned)f2bf(k0) | ((unsigned)f2bf(k1) << 16);
  *(unsigned*)&V[ob]  = vp;
}

// ---------------- V -> V^T per head: [h][s][d] -> [h][d][s] ----------------
__global__ void vtrans_kernel(const u16* __restrict__ V, u16* __restrict__ Vt){
  __shared__ u16 t[32][33];
  int h = blockIdx.z;
  int d0 = blockIdx.x*32, s0 = blockIdx.y*32;
  int tx = threadIdx.x, ty = threadIdx.y;
  const u16* Vh = V + (size_t)h*SEQL*HDIM;
  u16* Vth = Vt + (size_t)h*HDIM*SEQL;
  #pragma unroll
  for (int i=0;i<4;i++)
    t[ty*4+i][tx] = Vh[(size_t)(s0+ty*4+i)*HDIM + d0 + tx];
  __syncthreads();
  #pragma unroll
  for (int i=0;i<4;i++)
    Vth[(size_t)(d0+ty*4+i)*SEQL + s0 + tx] = t[tx][ty*4+i];
}

// ---------------- causal flash attention v2: 4 waves/block, 64 q-rows, LDS-staged K/V ----------------
// K tile [32][128] bf16, XOR-swizzled: 16B-block b' = b ^ (row&7)   (conflict-free reads)
// Vt tile [128][32] bf16, XOR-swizzled: 16B-block b' = b ^ (row&3)  (4-way residual)
// P per wave: 16 rows x stride 40 u16  (2-way = free on b128 read)
__global__ __launch_bounds__(256) void attn_kernel(const u16* __restrict__ Q, const u16* __restrict__ Kc,
                             const u16* __restrict__ Vt, u16* __restrict__ ctx)
{
  __shared__ u16 lK[32*128];
  __shared__ u16 lV[128*32];
  __shared__ u16 P[4*16*40];
  int qt = (gridDim.x - 1) - blockIdx.x;   // heavy blocks first
  int h = blockIdx.y;
  int tid = threadIdx.x;
  int lane = tid & 63;
  int wave = tid >> 6;
  int lr = lane & 15, lg = lane >> 4;
  int q0 = qt*64 + wave*16;
  const u16* Qh = Q  + (size_t)h*SEQL*HDIM;
  const u16* Kh = Kc + (size_t)h*SEQL*HDIM;
  const u16* Vh = Vt + (size_t)h*HDIM*SEQL;
  u16* Pw = &P[wave*640];

  bf16x8 qf[4];
  #pragma unroll
  for (int k32=0;k32<4;k32++)
    qf[k32] = *(const bf16x8*)&Qh[(size_t)(q0+lr)*HDIM + k32*32 + lg*8];

  f32x4 o[8] = {};
  float mrun[4], lrun[4];
  #pragma unroll
  for (int j=0;j<4;j++){ mrun[j] = -1e30f; lrun[j] = 0.f; }

  int tmax = (qt+1)*64;
  for (int t0 = 0; t0 < tmax; t0 += 32){
    __syncthreads();
    // stage K tile: 512 chunks of 16B
    #pragma unroll
    for (int i=0;i<2;i++){
      int c = i*256 + tid;
      int row = c >> 4, b = c & 15;
      int bp = b ^ (row & 7);
      gload_lds16(Kh + (size_t)(t0 + row)*HDIM + bp*8, &lK[c*8]);
    }
    // stage V^T tile: 512 chunks of 16B
    #pragma unroll
    for (int i=0;i<2;i++){
      int c = i*256 + tid;
      int d = c >> 2, b = c & 3;
      int bp = b ^ (d & 3);
      gload_lds16(Vh + (size_t)d*SEQL + t0 + bp*8, &lV[c*8]);
    }
    __syncthreads();
    if (t0 > q0 + 15) continue;   // causally masked for this wave (barriers already done)

    f32x4 s0v = {}, s1v = {};
    #pragma unroll
    for (int k32=0;k32<4;k32++){
      int r = lr;
      bf16x8 kf = *(const bf16x8*)&lK[r*128 + (((k32<<2)|lg) ^ (r&7))*8];
      s0v = __builtin_amdgcn_mfma_f32_16x16x32_bf16(qf[k32], kf, s0v, 0, 0, 0);
    }
    #pragma unroll
    for (int k32=0;k32<4;k32++){
      int r = 16 + lr;
      bf16x8 kf = *(const bf16x8*)&lK[r*128 + (((k32<<2)|lg) ^ (r&7))*8];
      s1v = __builtin_amdgcn_mfma_f32_16x16x32_bf16(qf[k32], kf, s1v, 0, 0, 0);
    }
    #pragma unroll
    for (int j=0;j<4;j++){
      int row = q0 + lg*4 + j;
      float a = ((t0 + lr)      > row) ? -1e30f : s0v[j];
      float b = ((t0 + 16 + lr) > row) ? -1e30f : s1v[j];
      float mx = fmaxf(a, b);
      mx = fmaxf(mx, __shfl_xor(mx, 1));
      mx = fmaxf(mx, __shfl_xor(mx, 2));
      mx = fmaxf(mx, __shfl_xor(mx, 4));
      mx = fmaxf(mx, __shfl_xor(mx, 8));
      float mnew = fmaxf(mrun[j], mx);
      float scl = expf(mrun[j] - mnew);
      float p0 = expf(a - mnew);
      float p1 = expf(b - mnew);
      float sm = p0 + p1;
      sm += __shfl_xor(sm, 1);
      sm += __shfl_xor(sm, 2);
      sm += __shfl_xor(sm, 4);
      sm += __shfl_xor(sm, 8);
      lrun[j] = lrun[j]*scl + sm;
      mrun[j] = mnew;
      #pragma unroll
      for (int n=0;n<8;n++) o[n][j] *= scl;
      Pw[(lg*4+j)*40 + lr]      = f2bf(p0);
      Pw[(lg*4+j)*40 + 16 + lr] = f2bf(p1);
    }
    bf16x8 pa = *(const bf16x8*)&Pw[lr*40 + lg*8];
    #pragma unroll
    for (int n=0;n<8;n++){
      int row = n*16 + lr;
      bf16x8 vf = *(const bf16x8*)&lV[row*32 + (lg ^ (row&3))*8];
      o[n] = __builtin_amdgcn_mfma_f32_16x16x32_bf16(pa, vf, o[n], 0, 0, 0);
    }
  }
  #pragma unroll
  for (int j=0;j<4;j++){
    float inv = 1.f / lrun[j];
    int srow = q0 + lg*4 + j;
    #pragma unroll
    for (int n=0;n<8;n++)
      ctx[(size_t)srow*HIDDEN + h*HDIM + n*16 + lr] = f2bf(o[n][j]*inv);
  }
}

extern "C" void kernel_launch(void* const* d_in, const int* in_sizes, int n_in,
                              void* d_out, int out_size, void* d_ws, size_t ws_size,
                              hipStream_t stream)
{
  const float* hs   = (const float*)d_in[0];
  const int*   pos  = (const int*)d_in[1];
  const float* Wqkv = (const float*)d_in[2];
  const float* bqkv = (const float*)d_in[3];
  const float* Wd   = (const float*)d_in[4];
  const float* bd   = (const float*)d_in[5];

  const size_t o_Wt  = 0;           // 33,554,432 B (4096x4096 bf16, reused 4x)
  const size_t o_hs  = 33554432;    // 16,777,216 B
  const size_t o_qkv = 50331648;    // 50,331,648 B (2048x12288 bf16); ctx aliases this
  const size_t o_Q   = 100663296;   // 16,777,216 B each
  const size_t o_K   = 117440512;
  const size_t o_V   = 134217728;
  const size_t o_Vt  = 150994944;
  const size_t need  = 167772160;
  if (ws_size < need){
    fprintf(stderr, "kernel_launch: ws too small: %zu < %zu\n", ws_size, need);
    return;
  }
  char* w = (char*)d_ws;
  u16* Wt  = (u16*)(w + o_Wt);
  u16* hsb = (u16*)(w + o_hs);
  u16* qkv = (u16*)(w + o_qkv);
  u16* ctx = (u16*)(w + o_qkv);   // alias: qkv dead after rope
  u16* Qs  = (u16*)(w + o_Q);
  u16* Ks  = (u16*)(w + o_K);
  u16* Vs  = (u16*)(w + o_V);
  u16* Vts = (u16*)(w + o_Vt);

  cast_hs_kernel<<<dim3(4096), dim3(256), 0, stream>>>(hs, hsb, SEQL*HIDDEN/8);

  for (int c = 0; c < 3; ++c){
    wtrans_kernel<<<dim3(128,128), dim3(32,8), 0, stream>>>(Wqkv, Wt, 12288, c*4096, 4096);
    gemm_bt_kernel<1><<<dim3(32,16), dim3(256), 0, stream>>>(
        hsb, Wt, bqkv + c*4096, (void*)(qkv + (size_t)c*4096), SEQL, 4096, HIDDEN, 12288);
  }

  rope_kernel<<<dim3(SEQL, NHEADS), dim3(64), 0, stream>>>(qkv, pos, Qs, Ks, Vs);
  vtrans_kernel<<<dim3(4, 64, NHEADS), dim3(32,8), 0, stream>>>(Vs, Vts);
  attn_kernel<<<dim3(SEQL/64, NHEADS), dim3(256), 0, stream>>>(Qs, Ks, Vts, ctx);

  wtrans_kernel<<<dim3(128,128), dim3(32,8), 0, stream>>>(Wd, Wt, 4096, 0, 4096);
  gemm_bt_kernel<0><<<dim3(32,16), dim3(256), 0, stream>>>(
      ctx, Wt, bd, d_out, SEQL, HIDDEN, HIDDEN, HIDDEN);
}

// Round 3
// 699.561 us; speedup vs baseline: 1.2633x; 1.1121x over previous
//
#include <hip/hip_runtime.h>
#include <cstdint>
#include <cstdio>

typedef unsigned short u16;
typedef short bf16x8 __attribute__((ext_vector_type(8)));
typedef float f32x4 __attribute__((ext_vector_type(4)));
typedef unsigned short u16x8 __attribute__((ext_vector_type(8)));

#define SEQL 2048
#define NHEADS 32
#define HDIM 128
#define HIDDEN 4096

__device__ __forceinline__ u16 f2bf(float x){
  union { float f; unsigned u; } v; v.f = x;
  unsigned r = v.u + 0x7fffu + ((v.u >> 16) & 1u);
  return (u16)(r >> 16);
}
__device__ __forceinline__ float bf2f(u16 x){
  union { unsigned u; float f; } v; v.u = ((unsigned)x) << 16;
  return v.f;
}

__device__ __forceinline__ void gload_lds16(const u16* g, u16* l){
  __builtin_amdgcn_global_load_lds((const __attribute__((address_space(1))) void*)g,
                                   (__attribute__((address_space(3))) void*)l, 16, 0, 0);
}

// ---------------- cast hidden_states f32 -> bf16 ----------------
__global__ void cast_hs_kernel(const float* __restrict__ in, u16* __restrict__ out, int n8){
  int i = blockIdx.x * blockDim.x + threadIdx.x;
  if (i >= n8) return;
  const float4* p = (const float4*)in + (size_t)i*2;
  float4 a = p[0], b = p[1];
  u16x8 o;
  o[0]=f2bf(a.x); o[1]=f2bf(a.y); o[2]=f2bf(a.z); o[3]=f2bf(a.w);
  o[4]=f2bf(b.x); o[5]=f2bf(b.y); o[6]=f2bf(b.z); o[7]=f2bf(b.w);
  *((u16x8*)out + i) = o;
}

// ---------------- transpose + cast weight chunk: W[K][Ntot] f32 -> Wt[n][k] bf16 ----------------
__global__ void wtrans_kernel(const float* __restrict__ W, u16* __restrict__ Wt,
                              int Ntot, int n0, int K){
  __shared__ float t[32][33];
  int tx = threadIdx.x, ty = threadIdx.y;
  int nn = blockIdx.x*32, k0 = blockIdx.y*32;
  #pragma unroll
  for (int i=0;i<4;i++)
    t[ty*4+i][tx] = W[(size_t)(k0+ty*4+i)*Ntot + n0 + nn + tx];
  __syncthreads();
  #pragma unroll
  for (int i=0;i<4;i++)
    Wt[(size_t)(nn+ty*4+i)*K + k0 + tx] = f2bf(t[tx][ty*4+i]);
}

// ---------------- m97-style GEMM: C = A[M][K] * Bt[N][K]^T + bias ----------------
template<int OUT_BF16>
__global__ __launch_bounds__(256) void gemm_bt_kernel(const u16* __restrict__ A, const u16* __restrict__ Bt,
                               const float* __restrict__ bias, void* __restrict__ Cv,
                               int M, int N, int K, int ldC)
{
  __shared__ u16 lA[128*32];
  __shared__ u16 lB[128*32];
  int tid = threadIdx.x;
  int lane = tid & 63;
  int wave = tid >> 6;
  int lr = lane & 15, lg = lane >> 4;
  int m0 = blockIdx.y*128, n0 = blockIdx.x*128;
  int wr = (wave >> 1)*64, wc = (wave & 1)*64;
  f32x4 acc[4][4] = {};
  for (int k0 = 0; k0 < K; k0 += 32){
    __syncthreads();
    #pragma unroll
    for (int i=0;i<2;i++){
      int c = i*256 + tid;
      gload_lds16(A + (size_t)(m0 + (c>>2))*K + k0 + (c&3)*8, &lA[c*8]);
    }
    #pragma unroll
    for (int i=0;i<2;i++){
      int c = i*256 + tid;
      gload_lds16(Bt + (size_t)(n0 + (c>>2))*K + k0 + (c&3)*8, &lB[c*8]);
    }
    __syncthreads();
    bf16x8 af[4], bfr[4];
    #pragma unroll
    for (int m=0;m<4;m++) af[m] = *(const bf16x8*)&lA[(wr + m*16 + lr)*32 + lg*8];
    #pragma unroll
    for (int n=0;n<4;n++) bfr[n] = *(const bf16x8*)&lB[(wc + n*16 + lr)*32 + lg*8];
    #pragma unroll
    for (int m=0;m<4;m++){
      #pragma unroll
      for (int n=0;n<4;n++){
        acc[m][n] = __builtin_amdgcn_mfma_f32_16x16x32_bf16(af[m], bfr[n], acc[m][n], 0, 0, 0);
      }
    }
  }
  #pragma unroll
  for (int m=0;m<4;m++){
    #pragma unroll
    for (int n=0;n<4;n++){
      #pragma unroll
      for (int j=0;j<4;j++){
        int gr = m0 + wr + m*16 + lg*4 + j;
        int gc = n0 + wc + n*16 + lr;
        float v = acc[m][n][j] + bias[gc];
        if (OUT_BF16) ((u16*)Cv)[(size_t)gr*ldC + gc] = f2bf(v);
        else          ((float*)Cv)[(size_t)gr*ldC + gc] = v;
      }
    }
  }
}

// ---------------- RoPE + relayout: qkv[s][h*384 + {0,128,256} + d] -> Q/K/V [h][s][d] ----------------
__global__ __launch_bounds__(64) void rope_kernel(const u16* __restrict__ qkv, const int* __restrict__ pos,
                            u16* __restrict__ Q, u16* __restrict__ Kc, u16* __restrict__ V)
{
  int s = blockIdx.x, h = blockIdx.y;
  int i = threadIdx.x;
  int half = i >> 5, ii = i & 31;
  int d0 = half*64 + ii*2;
  const u16* base = qkv + (size_t)s*12288 + h*384;
  unsigned qp = *(const unsigned*)&base[d0];
  unsigned kp = *(const unsigned*)&base[128 + d0];
  unsigned vp = *(const unsigned*)&base[256 + d0];
  float qe = bf2f((u16)qp), qo = bf2f((u16)(qp >> 16));
  float ke = bf2f((u16)kp), ko = bf2f((u16)(kp >> 16));
  float pv = (float)(pos[half*SEQL + s] + 1);
  float fr = exp2f(-(float)ii * 0.4152410118609203f);  // 10000^(-ii/32)
  float ang = pv * fr;
  float sn, cs; sincosf(ang, &sn, &cs);
  const float sc = 0.08838834764831845f;  // 1/sqrt(128), folded into Q
  float q0 = (qe*cs - qo*sn)*sc, q1 = (qe*sn + qo*cs)*sc;
  float k0 = ke*cs - ko*sn,      k1 = ke*sn + ko*cs;
  size_t ob = ((size_t)h*SEQL + s)*HDIM + d0;
  *(unsigned*)&Q[ob]  = (unsigned)f2bf(q0) | ((unsigned)f2bf(q1) << 16);
  *(unsigned*)&Kc[ob] = (unsigned)f2bf(k0) | ((unsigned)f2bf(k1) << 16);
  *(unsigned*)&V[ob]  = vp;
}

// ---------------- V -> V^T per head: [h][s][d] -> [h][d][s] ----------------
__global__ void vtrans_kernel(const u16* __restrict__ V, u16* __restrict__ Vt){
  __shared__ u16 t[32][33];
  int h = blockIdx.z;
  int d0 = blockIdx.x*32, s0 = blockIdx.y*32;
  int tx = threadIdx.x, ty = threadIdx.y;
  const u16* Vh = V + (size_t)h*SEQL*HDIM;
  u16* Vth = Vt + (size_t)h*HDIM*SEQL;
  #pragma unroll
  for (int i=0;i<4;i++)
    t[ty*4+i][tx] = Vh[(size_t)(s0+ty*4+i)*HDIM + d0 + tx];
  __syncthreads();
  #pragma unroll
  for (int i=0;i<4;i++)
    Vth[(size_t)(d0+ty*4+i)*SEQL + s0 + tx] = t[tx][ty*4+i];
}

// ---------------- causal flash attention v3 ----------------
// 4 waves/block, 64 q-rows/block, 16 q-rows/wave.
// Swapped QK^T: s = mfma(K_frag, Q_frag) -> lane holds 8 scores for ONE q-row
//   (q = q0 + (lane&15)), keys lane-local -> row reduce = local ops + 2 shfl.
// Defer-max rescale (THR=8). 2-phase double-buffered K/V staging (prefetch
// next tile before computing current; single __syncthreads per iteration).
__global__ __launch_bounds__(256) void attn_kernel(const u16* __restrict__ Q, const u16* __restrict__ Kc,
                             const u16* __restrict__ Vt, u16* __restrict__ ctx)
{
  __shared__ u16 lK[2][32*128];
  __shared__ u16 lV[2][128*32];
  __shared__ u16 P[4*16*40];
  int qt = (gridDim.x - 1) - blockIdx.x;   // heavy blocks first
  int h = blockIdx.y;
  int tid = threadIdx.x;
  int lane = tid & 63;
  int wave = tid >> 6;
  int lr = lane & 15, lg = lane >> 4;
  int q0 = qt*64 + wave*16;
  int q = q0 + lr;                          // this lane's q-row (softmax state)
  const u16* Qh = Q  + (size_t)h*SEQL*HDIM;
  const u16* Kh = Kc + (size_t)h*SEQL*HDIM;
  const u16* Vh = Vt + (size_t)h*HDIM*SEQL;
  u16* Pw = &P[wave*640];

  bf16x8 qf[4];
  #pragma unroll
  for (int k32=0;k32<4;k32++)
    qf[k32] = *(const bf16x8*)&Qh[(size_t)(q0+lr)*HDIM + k32*32 + lg*8];

  f32x4 o[8] = {};
  float mrun = -1e30f, lrun = 0.f;

  int nt = (qt+1)*2;   // 32-key tiles

  // stage(buf, t0)
  #define STAGE(BUF, T0) do {                                              \
    _Pragma("unroll")                                                      \
    for (int i=0;i<2;i++){                                                 \
      int c = i*256 + tid;                                                 \
      int row = c >> 4, b = c & 15;                                        \
      int bp = b ^ (row & 7);                                              \
      gload_lds16(Kh + (size_t)((T0) + row)*HDIM + bp*8, &lK[BUF][c*8]);   \
    }                                                                      \
    _Pragma("unroll")                                                      \
    for (int i=0;i<2;i++){                                                 \
      int c = i*256 + tid;                                                 \
      int d = c >> 2, b = c & 3;                                           \
      int bp = b ^ (d & 3);                                                \
      gload_lds16(Vh + (size_t)d*SEQL + (T0) + bp*8, &lV[BUF][c*8]);       \
    }                                                                      \
  } while(0)

  STAGE(0, 0);
  __syncthreads();

  for (int t = 0; t < nt; ++t){
    int t0 = t*32;
    int cur = t & 1;
    if (t+1 < nt) STAGE(cur^1, t0+32);   // prefetch overlaps compute below

    if (t0 <= q0 + 15){
      const u16* Kt  = &lK[cur][0];
      const u16* Vtl = &lV[cur][0];
      // QK^T swapped: C row = key, C col = q
      f32x4 s0v = {}, s1v = {};
      #pragma unroll
      for (int k32=0;k32<4;k32++){
        int r = lr;
        bf16x8 kf = *(const bf16x8*)&Kt[r*128 + (((k32<<2)|lg) ^ (r&7))*8];
        s0v = __builtin_amdgcn_mfma_f32_16x16x32_bf16(kf, qf[k32], s0v, 0, 0, 0);
      }
      #pragma unroll
      for (int k32=0;k32<4;k32++){
        int r = 16 + lr;
        bf16x8 kf = *(const bf16x8*)&Kt[r*128 + (((k32<<2)|lg) ^ (r&7))*8];
        s1v = __builtin_amdgcn_mfma_f32_16x16x32_bf16(kf, qf[k32], s1v, 0, 0, 0);
      }
      // lane holds: s0v[j] = S[key t0+lg*4+j][q], s1v[j] = S[key t0+16+lg*4+j][q]
      float sv[8];
      int kb = t0 + lg*4;
      #pragma unroll
      for (int j=0;j<4;j++){
        sv[j]   = (kb + j      > q) ? -1e30f : s0v[j];
        sv[4+j] = (kb + 16 + j > q) ? -1e30f : s1v[j];
      }
      float mx = fmaxf(fmaxf(fmaxf(sv[0],sv[1]),fmaxf(sv[2],sv[3])),
                       fmaxf(fmaxf(sv[4],sv[5]),fmaxf(sv[6],sv[7])));
      mx = fmaxf(mx, __shfl_xor(mx, 16));
      mx = fmaxf(mx, __shfl_xor(mx, 32));
      if (!__all(mx <= mrun + 8.f)){
        float mnew = fmaxf(mrun, mx);
        float scl = expf(mrun - mnew);
        lrun *= scl;
        mrun = mnew;
        float sj[4];
        #pragma unroll
        for (int j=0;j<4;j++) sj[j] = __shfl(scl, lg*4 + j);
        #pragma unroll
        for (int n=0;n<8;n++){
          #pragma unroll
          for (int j=0;j<4;j++) o[n][j] *= sj[j];
        }
      }
      float p[8];
      #pragma unroll
      for (int j=0;j<8;j++) p[j] = expf(sv[j] - mrun);
      float sm = (p[0]+p[1]) + (p[2]+p[3]) + ((p[4]+p[5]) + (p[6]+p[7]));
      sm += __shfl_xor(sm, 16);
      sm += __shfl_xor(sm, 32);
      lrun += sm;
      // P[q-row = lr][key col]: lane writes cols lg*4..+3 and 16+lg*4..+3
      uint2 w0, w1;
      w0.x = (unsigned)f2bf(p[0]) | ((unsigned)f2bf(p[1]) << 16);
      w0.y = (unsigned)f2bf(p[2]) | ((unsigned)f2bf(p[3]) << 16);
      w1.x = (unsigned)f2bf(p[4]) | ((unsigned)f2bf(p[5]) << 16);
      w1.y = (unsigned)f2bf(p[6]) | ((unsigned)f2bf(p[7]) << 16);
      *(uint2*)&Pw[lr*40 + lg*4]      = w0;
      *(uint2*)&Pw[lr*40 + 16 + lg*4] = w1;
      // PV: A = P (rows=q), B = V^T tile
      bf16x8 pa = *(const bf16x8*)&Pw[lr*40 + lg*8];
      #pragma unroll
      for (int n=0;n<8;n++){
        int row = n*16 + lr;
        bf16x8 vf = *(const bf16x8*)&Vtl[row*32 + (lg ^ (row&3))*8];
        o[n] = __builtin_amdgcn_mfma_f32_16x16x32_bf16(pa, vf, o[n], 0, 0, 0);
      }
    }
    __syncthreads();   // drains vmcnt (prefetch) + protects buffer swap
  }
  #undef STAGE

  #pragma unroll
  for (int j=0;j<4;j++){
    float lj = __shfl(lrun, lg*4 + j);   // lrun for q-row q0+lg*4+j
    float inv = 1.f / lj;
    int srow = q0 + lg*4 + j;
    #pragma unroll
    for (int n=0;n<8;n++)
      ctx[(size_t)srow*HIDDEN + h*HDIM + n*16 + lr] = f2bf(o[n][j]*inv);
  }
}

extern "C" void kernel_launch(void* const* d_in, const int* in_sizes, int n_in,
                              void* d_out, int out_size, void* d_ws, size_t ws_size,
                              hipStream_t stream)
{
  const float* hs   = (const float*)d_in[0];
  const int*   pos  = (const int*)d_in[1];
  const float* Wqkv = (const float*)d_in[2];
  const float* bqkv = (const float*)d_in[3];
  const float* Wd   = (const float*)d_in[4];
  const float* bd   = (const float*)d_in[5];

  const size_t o_Wt  = 0;           // 33,554,432 B (4096x4096 bf16, reused 4x)
  const size_t o_hs  = 33554432;    // 16,777,216 B
  const size_t o_qkv = 50331648;    // 50,331,648 B (2048x12288 bf16); ctx aliases this
  const size_t o_Q   = 100663296;   // 16,777,216 B each
  const size_t o_K   = 117440512;
  const size_t o_V   = 134217728;
  const size_t o_Vt  = 150994944;
  const size_t need  = 167772160;
  if (ws_size < need){
    fprintf(stderr, "kernel_launch: ws too small: %zu < %zu\n", ws_size, need);
    return;
  }
  char* w = (char*)d_ws;
  u16* Wt  = (u16*)(w + o_Wt);
  u16* hsb = (u16*)(w + o_hs);
  u16* qkv = (u16*)(w + o_qkv);
  u16* ctx = (u16*)(w + o_qkv);   // alias: qkv dead after rope
  u16* Qs  = (u16*)(w + o_Q);
  u16* Ks  = (u16*)(w + o_K);
  u16* Vs  = (u16*)(w + o_V);
  u16* Vts = (u16*)(w + o_Vt);

  cast_hs_kernel<<<dim3(4096), dim3(256), 0, stream>>>(hs, hsb, SEQL*HIDDEN/8);

  for (int c = 0; c < 3; ++c){
    wtrans_kernel<<<dim3(128,128), dim3(32,8), 0, stream>>>(Wqkv, Wt, 12288, c*4096, 4096);
    gemm_bt_kernel<1><<<dim3(32,16), dim3(256), 0, stream>>>(
        hsb, Wt, bqkv + c*4096, (void*)(qkv + (size_t)c*4096), SEQL, 4096, HIDDEN, 12288);
  }

  rope_kernel<<<dim3(SEQL, NHEADS), dim3(64), 0, stream>>>(qkv, pos, Qs, Ks, Vs);
  vtrans_kernel<<<dim3(4, 64, NHEADS), dim3(32,8), 0, stream>>>(Vs, Vts);
  attn_kernel<<<dim3(SEQL/64, NHEADS), dim3(256), 0, stream>>>(Qs, Ks, Vts, ctx);

  wtrans_kernel<<<dim3(128,128), dim3(32,8), 0, stream>>>(Wd, Wt, 4096, 0, 4096);
  gemm_bt_kernel<0><<<dim3(32,16), dim3(256), 0, stream>>>(
      ctx, Wt, bd, d_out, SEQL, HIDDEN, HIDDEN, HIDDEN);
}

// Round 4
// 579.183 us; speedup vs baseline: 1.5258x; 1.2078x over previous
//
#include <hip/hip_runtime.h>
#include <cstdint>
#include <cstdio>

typedef unsigned short u16;
typedef short bf16x8 __attribute__((ext_vector_type(8)));
typedef float f32x4 __attribute__((ext_vector_type(4)));
typedef unsigned short u16x8 __attribute__((ext_vector_type(8)));

#define SEQL 2048
#define NHEADS 32
#define HDIM 128
#define HIDDEN 4096

__device__ __forceinline__ u16 f2bf(float x){
  union { float f; unsigned u; } v; v.f = x;
  unsigned r = v.u + 0x7fffu + ((v.u >> 16) & 1u);
  return (u16)(r >> 16);
}
__device__ __forceinline__ float bf2f(u16 x){
  union { unsigned u; float f; } v; v.u = ((unsigned)x) << 16;
  return v.f;
}

__device__ __forceinline__ void gload_lds16(const u16* g, u16* l){
  __builtin_amdgcn_global_load_lds((const __attribute__((address_space(1))) void*)g,
                                   (__attribute__((address_space(3))) void*)l, 16, 0, 0);
}

// ---------------- cast hidden_states f32 -> bf16 ----------------
__global__ void cast_hs_kernel(const float* __restrict__ in, u16* __restrict__ out, int n8){
  int i = blockIdx.x * blockDim.x + threadIdx.x;
  if (i >= n8) return;
  const float4* p = (const float4*)in + (size_t)i*2;
  float4 a = p[0], b = p[1];
  u16x8 o;
  o[0]=f2bf(a.x); o[1]=f2bf(a.y); o[2]=f2bf(a.z); o[3]=f2bf(a.w);
  o[4]=f2bf(b.x); o[5]=f2bf(b.y); o[6]=f2bf(b.z); o[7]=f2bf(b.w);
  *((u16x8*)out + i) = o;
}

// ---------------- transpose + cast weight chunk: W[K][Ntot] f32 -> Wt[n][k] bf16 ----------------
__global__ void wtrans_kernel(const float* __restrict__ W, u16* __restrict__ Wt,
                              int Ntot, int n0, int K){
  __shared__ float t[32][33];
  int tx = threadIdx.x, ty = threadIdx.y;
  int nn = blockIdx.x*32, k0 = blockIdx.y*32;
  #pragma unroll
  for (int i=0;i<4;i++)
    t[ty*4+i][tx] = W[(size_t)(k0+ty*4+i)*Ntot + n0 + nn + tx];
  __syncthreads();
  #pragma unroll
  for (int i=0;i<4;i++)
    Wt[(size_t)(nn+ty*4+i)*K + k0 + tx] = f2bf(t[tx][ty*4+i]);
}

// ---------------- pipelined GEMM: C = A[M][K] * Bt[N][K]^T + bias ----------------
// BM=128, BN=256, BK=64. 512 threads = 8 waves (2M x 4N), wave tile 64x64.
// Triple-buffered LDS (3 x 48KB), staging 2 tiles ahead, counted vmcnt(6)
// (never 0 in main loop), raw s_barrier, XOR-swizzled LDS (block ^= row&7),
// setprio around MFMA, XCD-swizzled n-major block order.
template<int OUT_BF16>
__global__ __launch_bounds__(512) void gemm3_kernel(const u16* __restrict__ A, const u16* __restrict__ Bt,
                              const float* __restrict__ bias, void* __restrict__ Cv,
                              int K, int ldC, int NBM)
{
  extern __shared__ u16 lds[];   // 3 * 24576 u16 = 147456 B
  int tid = threadIdx.x;
  int lane = tid & 63;
  int wave = tid >> 6;
  int lr = lane & 15, lg = lane >> 4;
  int wm = wave >> 2, wn = wave & 3;

  // XCD swizzle (nwg % 8 == 0 for all our grids), n-major decomposition
  int nwg = gridDim.x;
  int cpx = nwg >> 3;
  int b0 = blockIdx.x;
  int swz = (b0 & 7) * cpx + (b0 >> 3);
  int bm = swz % NBM, bn = swz / NBM;
  int m0 = bm * 128, n0 = bn * 256;

  int NT = K >> 6;

  // per-thread staging chunks: A: c = tid + i*512 (i=0..1); B: c = tid + i*512 (i=0..3)
  unsigned offA[2]; int ldsA[2];
  #pragma unroll
  for (int i=0;i<2;i++){
    int c = tid + i*512;
    int row = c >> 3, blk = c & 7;
    offA[i] = (unsigned)(m0 + row)*K + (unsigned)((blk ^ (row & 7))*8);
    ldsA[i] = c*8;
  }
  unsigned offB[4]; int ldsB[4];
  #pragma unroll
  for (int i=0;i<4;i++){
    int c = tid + i*512;
    int row = c >> 3, blk = c & 7;
    offB[i] = (unsigned)(n0 + row)*K + (unsigned)((blk ^ (row & 7))*8);
    ldsB[i] = c*8;
  }

  // fragment read offsets (element units). row&7 == lr&7 for all frags.
  int colk[2];
  colk[0] = ((lg)     ^ (lr & 7))*8;
  colk[1] = ((4 + lg) ^ (lr & 7))*8;
  int rA[4], rB[4];
  #pragma unroll
  for (int m=0;m<4;m++) rA[m] = (wm*64 + m*16 + lr)*64;
  #pragma unroll
  for (int n=0;n<4;n++) rB[n] = (wn*64 + n*16 + lr)*64;

  f32x4 acc[4][4] = {};

  // prologue: stage tiles 0 and 1
  #pragma unroll
  for (int tt=0; tt<2; ++tt){
    u16* dA = lds + tt*24576;
    u16* dB = dA + 8192;
    int k0 = tt*64;
    #pragma unroll
    for (int i=0;i<2;i++) gload_lds16(A + offA[i] + k0, dA + ldsA[i]);
    #pragma unroll
    for (int i=0;i<4;i++) gload_lds16(Bt + offB[i] + k0, dB + ldsB[i]);
  }
  asm volatile("s_waitcnt vmcnt(6)" ::: "memory");   // tile 0 landed
  asm volatile("s_barrier" ::: "memory");

  int p = 0, s2 = 2;
  for (int t = 0; t < NT; ++t){
    const u16* bA = lds + p*24576;
    const u16* bB = bA + 8192;
    u16* dA = lds + s2*24576;
    u16* dB = dA + 8192;
    bool st = (t + 2) < NT;
    int k2 = (t + 2) << 6;

    // ---------- phase 0: n-cols 0,1 ----------
    bf16x8 a_[4][2], bf0[2][2];
    #pragma unroll
    for (int m=0;m<4;m++){
      a_[m][0] = *(const bf16x8*)&bA[rA[m] + colk[0]];
      a_[m][1] = *(const bf16x8*)&bA[rA[m] + colk[1]];
    }
    #pragma unroll
    for (int n=0;n<2;n++){
      bf0[n][0] = *(const bf16x8*)&bB[rB[n] + colk[0]];
      bf0[n][1] = *(const bf16x8*)&bB[rB[n] + colk[1]];
    }
    if (st){
      gload_lds16(A + offA[0] + k2, dA + ldsA[0]);
      gload_lds16(A + offA[1] + k2, dA + ldsA[1]);
      gload_lds16(Bt + offB[0] + k2, dB + ldsB[0]);
    }
    asm volatile("s_barrier" ::: "memory");
    asm volatile("s_waitcnt lgkmcnt(0)" ::: "memory");
    __builtin_amdgcn_sched_barrier(0);
    __builtin_amdgcn_s_setprio(1);
    #pragma unroll
    for (int m=0;m<4;m++){
      #pragma unroll
      for (int n=0;n<2;n++){
        acc[m][n] = __builtin_amdgcn_mfma_f32_16x16x32_bf16(a_[m][0], bf0[n][0], acc[m][n], 0, 0, 0);
        acc[m][n] = __builtin_amdgcn_mfma_f32_16x16x32_bf16(a_[m][1], bf0[n][1], acc[m][n], 0, 0, 0);
      }
    }
    __builtin_amdgcn_s_setprio(0);
    asm volatile("s_barrier" ::: "memory");

    // ---------- phase 1: n-cols 2,3 ----------
    bf16x8 bf1[2][2];
    #pragma unroll
    for (int n=0;n<2;n++){
      bf1[n][0] = *(const bf16x8*)&bB[rB[n+2] + colk[0]];
      bf1[n][1] = *(const bf16x8*)&bB[rB[n+2] + colk[1]];
    }
    if (st){
      gload_lds16(Bt + offB[1] + k2, dB + ldsB[1]);
      gload_lds16(Bt + offB[2] + k2, dB + ldsB[2]);
      gload_lds16(Bt + offB[3] + k2, dB + ldsB[3]);
    }
    asm volatile("s_barrier" ::: "memory");
    asm volatile("s_waitcnt lgkmcnt(0)" ::: "memory");
    __builtin_amdgcn_sched_barrier(0);
    __builtin_amdgcn_s_setprio(1);
    #pragma unroll
    for (int m=0;m<4;m++){
      #pragma unroll
      for (int n=0;n<2;n++){
        acc[m][n+2] = __builtin_amdgcn_mfma_f32_16x16x32_bf16(a_[m][0], bf1[n][0], acc[m][n+2], 0, 0, 0);
        acc[m][n+2] = __builtin_amdgcn_mfma_f32_16x16x32_bf16(a_[m][1], bf1[n][1], acc[m][n+2], 0, 0, 0);
      }
    }
    __builtin_amdgcn_s_setprio(0);
    if (st) asm volatile("s_waitcnt vmcnt(6)" ::: "memory");   // tile t+1 landed; t+2 in flight
    else    asm volatile("s_waitcnt vmcnt(0)" ::: "memory");   // epilogue drain
    asm volatile("s_barrier" ::: "memory");

    p = (p == 2) ? 0 : p + 1;
    s2 = (s2 == 2) ? 0 : s2 + 1;
  }

  // epilogue: C += bias
  #pragma unroll
  for (int m=0;m<4;m++){
    #pragma unroll
    for (int n=0;n<4;n++){
      #pragma unroll
      for (int j=0;j<4;j++){
        int gr = m0 + wm*64 + m*16 + lg*4 + j;
        int gc = n0 + wn*64 + n*16 + lr;
        float v = acc[m][n][j] + bias[gc];
        if (OUT_BF16) ((u16*)Cv)[(size_t)gr*ldC + gc] = f2bf(v);
        else          ((float*)Cv)[(size_t)gr*ldC + gc] = v;
      }
    }
  }
}

// ---------------- RoPE + relayout: qkv[s][h*384 + {0,128,256} + d] -> Q/K/V [h][s][d] ----------------
__global__ __launch_bounds__(64) void rope_kernel(const u16* __restrict__ qkv, const int* __restrict__ pos,
                            u16* __restrict__ Q, u16* __restrict__ Kc, u16* __restrict__ V)
{
  int s = blockIdx.x, h = blockIdx.y;
  int i = threadIdx.x;
  int half = i >> 5, ii = i & 31;
  int d0 = half*64 + ii*2;
  const u16* base = qkv + (size_t)s*12288 + h*384;
  unsigned qp = *(const unsigned*)&base[d0];
  unsigned kp = *(const unsigned*)&base[128 + d0];
  unsigned vp = *(const unsigned*)&base[256 + d0];
  float qe = bf2f((u16)qp), qo = bf2f((u16)(qp >> 16));
  float ke = bf2f((u16)kp), ko = bf2f((u16)(kp >> 16));
  float pv = (float)(pos[half*SEQL + s] + 1);
  float fr = exp2f(-(float)ii * 0.4152410118609203f);  // 10000^(-ii/32)
  float ang = pv * fr;
  float sn, cs; sincosf(ang, &sn, &cs);
  const float sc = 0.08838834764831845f;  // 1/sqrt(128), folded into Q
  float q0 = (qe*cs - qo*sn)*sc, q1 = (qe*sn + qo*cs)*sc;
  float k0 = ke*cs - ko*sn,      k1 = ke*sn + ko*cs;
  size_t ob = ((size_t)h*SEQL + s)*HDIM + d0;
  *(unsigned*)&Q[ob]  = (unsigned)f2bf(q0) | ((unsigned)f2bf(q1) << 16);
  *(unsigned*)&Kc[ob] = (unsigned)f2bf(k0) | ((unsigned)f2bf(k1) << 16);
  *(unsigned*)&V[ob]  = vp;
}

// ---------------- V -> V^T per head: [h][s][d] -> [h][d][s] ----------------
__global__ void vtrans_kernel(const u16* __restrict__ V, u16* __restrict__ Vt){
  __shared__ u16 t[32][33];
  int h = blockIdx.z;
  int d0 = blockIdx.x*32, s0 = blockIdx.y*32;
  int tx = threadIdx.x, ty = threadIdx.y;
  const u16* Vh = V + (size_t)h*SEQL*HDIM;
  u16* Vth = Vt + (size_t)h*HDIM*SEQL;
  #pragma unroll
  for (int i=0;i<4;i++)
    t[ty*4+i][tx] = Vh[(size_t)(s0+ty*4+i)*HDIM + d0 + tx];
  __syncthreads();
  #pragma unroll
  for (int i=0;i<4;i++)
    Vth[(size_t)(d0+ty*4+i)*SEQL + s0 + tx] = t[tx][ty*4+i];
}

// ---------------- causal flash attention v3 (unchanged from R3) ----------------
__global__ __launch_bounds__(256) void attn_kernel(const u16* __restrict__ Q, const u16* __restrict__ Kc,
                             const u16* __restrict__ Vt, u16* __restrict__ ctx)
{
  __shared__ u16 lK[2][32*128];
  __shared__ u16 lV[2][128*32];
  __shared__ u16 P[4*16*40];
  int qt = (gridDim.x - 1) - blockIdx.x;   // heavy blocks first
  int h = blockIdx.y;
  int tid = threadIdx.x;
  int lane = tid & 63;
  int wave = tid >> 6;
  int lr = lane & 15, lg = lane >> 4;
  int q0 = qt*64 + wave*16;
  int q = q0 + lr;                          // this lane's q-row (softmax state)
  const u16* Qh = Q  + (size_t)h*SEQL*HDIM;
  const u16* Kh = Kc + (size_t)h*SEQL*HDIM;
  const u16* Vh = Vt + (size_t)h*HDIM*SEQL;
  u16* Pw = &P[wave*640];

  bf16x8 qf[4];
  #pragma unroll
  for (int k32=0;k32<4;k32++)
    qf[k32] = *(const bf16x8*)&Qh[(size_t)(q0+lr)*HDIM + k32*32 + lg*8];

  f32x4 o[8] = {};
  float mrun = -1e30f, lrun = 0.f;

  int nt = (qt+1)*2;   // 32-key tiles

  #define STAGE(BUF, T0) do {                                              \
    _Pragma("unroll")                                                      \
    for (int i=0;i<2;i++){                                                 \
      int c = i*256 + tid;                                                 \
      int row = c >> 4, b = c & 15;                                        \
      int bp = b ^ (row & 7);                                              \
      gload_lds16(Kh + (size_t)((T0) + row)*HDIM + bp*8, &lK[BUF][c*8]);   \
    }                                                                      \
    _Pragma("unroll")                                                      \
    for (int i=0;i<2;i++){                                                 \
      int c = i*256 + tid;                                                 \
      int d = c >> 2, b = c & 3;                                           \
      int bp = b ^ (d & 3);                                                \
      gload_lds16(Vh + (size_t)d*SEQL + (T0) + bp*8, &lV[BUF][c*8]);       \
    }                                                                      \
  } while(0)

  STAGE(0, 0);
  __syncthreads();

  for (int t = 0; t < nt; ++t){
    int t0 = t*32;
    int cur = t & 1;
    if (t+1 < nt) STAGE(cur^1, t0+32);   // prefetch overlaps compute below

    if (t0 <= q0 + 15){
      const u16* Kt  = &lK[cur][0];
      const u16* Vtl = &lV[cur][0];
      f32x4 s0v = {}, s1v = {};
      #pragma unroll
      for (int k32=0;k32<4;k32++){
        int r = lr;
        bf16x8 kf = *(const bf16x8*)&Kt[r*128 + (((k32<<2)|lg) ^ (r&7))*8];
        s0v = __builtin_amdgcn_mfma_f32_16x16x32_bf16(kf, qf[k32], s0v, 0, 0, 0);
      }
      #pragma unroll
      for (int k32=0;k32<4;k32++){
        int r = 16 + lr;
        bf16x8 kf = *(const bf16x8*)&Kt[r*128 + (((k32<<2)|lg) ^ (r&7))*8];
        s1v = __builtin_amdgcn_mfma_f32_16x16x32_bf16(kf, qf[k32], s1v, 0, 0, 0);
      }
      float sv[8];
      int kb = t0 + lg*4;
      #pragma unroll
      for (int j=0;j<4;j++){
        sv[j]   = (kb + j      > q) ? -1e30f : s0v[j];
        sv[4+j] = (kb + 16 + j > q) ? -1e30f : s1v[j];
      }
      float mx = fmaxf(fmaxf(fmaxf(sv[0],sv[1]),fmaxf(sv[2],sv[3])),
                       fmaxf(fmaxf(sv[4],sv[5]),fmaxf(sv[6],sv[7])));
      mx = fmaxf(mx, __shfl_xor(mx, 16));
      mx = fmaxf(mx, __shfl_xor(mx, 32));
      if (!__all(mx <= mrun + 8.f)){
        float mnew = fmaxf(mrun, mx);
        float scl = expf(mrun - mnew);
        lrun *= scl;
        mrun = mnew;
        float sj[4];
        #pragma unroll
        for (int j=0;j<4;j++) sj[j] = __shfl(scl, lg*4 + j);
        #pragma unroll
        for (int n=0;n<8;n++){
          #pragma unroll
          for (int j=0;j<4;j++) o[n][j] *= sj[j];
        }
      }
      float p[8];
      #pragma unroll
      for (int j=0;j<8;j++) p[j] = expf(sv[j] - mrun);
      float sm = (p[0]+p[1]) + (p[2]+p[3]) + ((p[4]+p[5]) + (p[6]+p[7]));
      sm += __shfl_xor(sm, 16);
      sm += __shfl_xor(sm, 32);
      lrun += sm;
      uint2 w0, w1;
      w0.x = (unsigned)f2bf(p[0]) | ((unsigned)f2bf(p[1]) << 16);
      w0.y = (unsigned)f2bf(p[2]) | ((unsigned)f2bf(p[3]) << 16);
      w1.x = (unsigned)f2bf(p[4]) | ((unsigned)f2bf(p[5]) << 16);
      w1.y = (unsigned)f2bf(p[6]) | ((unsigned)f2bf(p[7]) << 16);
      *(uint2*)&Pw[lr*40 + lg*4]      = w0;
      *(uint2*)&Pw[lr*40 + 16 + lg*4] = w1;
      bf16x8 pa = *(const bf16x8*)&Pw[lr*40 + lg*8];
      #pragma unroll
      for (int n=0;n<8;n++){
        int row = n*16 + lr;
        bf16x8 vf = *(const bf16x8*)&Vtl[row*32 + (lg ^ (row&3))*8];
        o[n] = __builtin_amdgcn_mfma_f32_16x16x32_bf16(pa, vf, o[n], 0, 0, 0);
      }
    }
    __syncthreads();
  }
  #undef STAGE

  #pragma unroll
  for (int j=0;j<4;j++){
    float lj = __shfl(lrun, lg*4 + j);
    float inv = 1.f / lj;
    int srow = q0 + lg*4 + j;
    #pragma unroll
    for (int n=0;n<8;n++)
      ctx[(size_t)srow*HIDDEN + h*HDIM + n*16 + lr] = f2bf(o[n][j]*inv);
  }
}

extern "C" void kernel_launch(void* const* d_in, const int* in_sizes, int n_in,
                              void* d_out, int out_size, void* d_ws, size_t ws_size,
                              hipStream_t stream)
{
  const float* hs   = (const float*)d_in[0];
  const int*   pos  = (const int*)d_in[1];
  const float* Wqkv = (const float*)d_in[2];
  const float* bqkv = (const float*)d_in[3];
  const float* Wd   = (const float*)d_in[4];
  const float* bd   = (const float*)d_in[5];

  // ws layout (need = 167772160 B, same as prior rounds):
  //   [0,        16.78M)  hsb
  //   [16.78M,   67.11M)  qkv (bf16, ldC=12288); ctx aliases after rope
  //   [67.11M,  167.77M)  Wt_qkv [12288][4096] bf16  (dead after QKV GEMM)
  //     aliased after QKV GEMM:
  //   [67.11M,   83.89M)  Q    [83.89M, 100.66M) K
  //   [100.66M, 117.44M)  V    [117.44M, 134.22M) Vt
  //   [134.22M, 167.77M)  Wt_dense [4096][4096] bf16
  const size_t o_hs  = 0;
  const size_t o_qkv = 16777216;
  const size_t o_Wtq = 67108864;
  const size_t o_Q   = 67108864;
  const size_t o_K   = 83886080;
  const size_t o_V   = 100663296;
  const size_t o_Vt  = 117440512;
  const size_t o_Wtd = 134217728;
  const size_t need  = 167772160;
  if (ws_size < need){
    fprintf(stderr, "kernel_launch: ws too small: %zu < %zu\n", ws_size, need);
    return;
  }
  char* w = (char*)d_ws;
  u16* hsb = (u16*)(w + o_hs);
  u16* qkv = (u16*)(w + o_qkv);
  u16* ctx = (u16*)(w + o_qkv);
  u16* Wtq = (u16*)(w + o_Wtq);
  u16* Qs  = (u16*)(w + o_Q);
  u16* Ks  = (u16*)(w + o_K);
  u16* Vs  = (u16*)(w + o_V);
  u16* Vts = (u16*)(w + o_Vt);
  u16* Wtd = (u16*)(w + o_Wtd);

  const size_t gemm_lds = 3*24576*sizeof(u16);   // 147456 B

  cast_hs_kernel<<<dim3(4096), dim3(256), 0, stream>>>(hs, hsb, SEQL*HIDDEN/8);
  wtrans_kernel<<<dim3(384,128), dim3(32,8), 0, stream>>>(Wqkv, Wtq, 12288, 0, 4096);

  // QKV GEMM: [2048 x 4096] x [4096 x 12288] -> qkv (bf16), fused single launch
  gemm3_kernel<1><<<dim3(16*48), dim3(512), gemm_lds, stream>>>(
      hsb, Wtq, bqkv, (void*)qkv, HIDDEN, 12288, 16);

  // dense weight transpose (after QKV GEMM: region overlaps Wt_qkv tail)
  wtrans_kernel<<<dim3(128,128), dim3(32,8), 0, stream>>>(Wd, Wtd, 4096, 0, 4096);

  rope_kernel<<<dim3(SEQL, NHEADS), dim3(64), 0, stream>>>(qkv, pos, Qs, Ks, Vs);
  vtrans_kernel<<<dim3(4, 64, NHEADS), dim3(32,8), 0, stream>>>(Vs, Vts);
  attn_kernel<<<dim3(SEQL/64, NHEADS), dim3(256), 0, stream>>>(Qs, Ks, Vts, ctx);

  // dense GEMM: [2048 x 4096] x [4096 x 4096] -> d_out (f32)
  gemm3_kernel<0><<<dim3(16*16), dim3(512), gemm_lds, stream>>>(
      ctx, Wtd, bd, d_out, HIDDEN, HIDDEN, 16);
}